// Round 6
// baseline (398.127 us; speedup 1.0000x reference)
//
#include <hip/hip_runtime.h>
#include <math.h>

#define CDIV(a,b) (((a)+(b)-1)/(b))
#define SEGCAP 768  // max edges per 32-node group in LDS fast path (mean 384)

typedef unsigned short ushort_t;

__device__ __forceinline__ ushort_t f2bf(float x) {
  unsigned u = __float_as_uint(x);
  unsigned r = (u + 0x7FFFu + ((u >> 16) & 1u)) >> 16;
  return (ushort_t)r;
}
__device__ __forceinline__ float bf2f(ushort_t s) {
  return __uint_as_float(((unsigned)s) << 16);
}

// ---------------------------------------------------------------------------
// K1: feat = h @ fc_w.T (N x 128) -> bf16; fused el/er epilogue (LDS reduce).
// ---------------------------------------------------------------------------
__global__ __launch_bounds__(256) void k_gemm(const float* __restrict__ hm,
                                              const float* __restrict__ w,
                                              const float* __restrict__ al,
                                              const float* __restrict__ ar,
                                              ushort_t* __restrict__ featbf,
                                              float* __restrict__ el,
                                              float* __restrict__ er, int n) {
  __shared__ float wl[128 * 68];
  __shared__ float hl[64 * 68];
  const int t = threadIdx.x;
  const int base = blockIdx.x * 64;
  const int cg = t & 7;
  const int np = t >> 3;
  float acc0[16], acc1[16];
#pragma unroll
  for (int d = 0; d < 16; ++d) { acc0[d] = 0.f; acc1[d] = 0.f; }

  for (int half = 0; half < 2; ++half) {
    const int k0q = half * 16;
    if (half) __syncthreads();
    for (int r = 0; r < 8; ++r) {
      int f = t + 256 * r;
      int row = f >> 4, c4 = f & 15;
      float4 v = ((const float4*)w)[row * 32 + k0q + c4];
      float* dp = &wl[row * 68 + c4 * 4];
      dp[0] = v.x; dp[1] = v.y; dp[2] = v.z; dp[3] = v.w;
    }
    for (int r = 0; r < 4; ++r) {
      int f = t + 256 * r;
      int row = f >> 4, c4 = f & 15;
      int nidx = base + row;
      float4 v = make_float4(0.f, 0.f, 0.f, 0.f);
      if (nidx < n) v = ((const float4*)hm)[nidx * 32 + k0q + c4];
      float* dp = &hl[row * 68 + c4 * 4];
      dp[0] = v.x; dp[1] = v.y; dp[2] = v.z; dp[3] = v.w;
    }
    __syncthreads();
    const float* h0 = &hl[(np * 2) * 68];
    const float* h1 = &hl[(np * 2 + 1) * 68];
    for (int c = 0; c < 16; ++c) {
      int k = c * 4;
      float4 a0 = *(const float4*)&h0[k];
      float4 a1 = *(const float4*)&h1[k];
#pragma unroll
      for (int d = 0; d < 16; ++d) {
        float4 wv = *(const float4*)&wl[(cg + 8 * d) * 68 + k];
        acc0[d] += a0.x * wv.x + a0.y * wv.y + a0.z * wv.z + a0.w * wv.w;
        acc1[d] += a1.x * wv.x + a1.y * wv.y + a1.z * wv.z + a1.w * wv.w;
      }
    }
  }
  int n0 = base + np * 2, n1 = n0 + 1;
  if (n0 < n) {
#pragma unroll
    for (int d = 0; d < 16; ++d) featbf[(size_t)n0 * 128 + cg + 8 * d] = f2bf(acc0[d]);
  }
  if (n1 < n) {
#pragma unroll
    for (int d = 0; d < 16; ++d) featbf[(size_t)n1 * 128 + cg + 8 * d] = f2bf(acc1[d]);
  }
  // ---- fused el/er: reuse wl as elL[64*8] ++ erL[64*8] ----
  __syncthreads();
  float* elL = wl;
  float* erL = wl + 512;
  for (int k = t; k < 1024; k += 256) wl[k] = 0.f;
  __syncthreads();
  // head h owns features hd in [16h,16h+16); this thread's d-pair for head h
  // is d=2h,2h+1 (hd=cg+8d). Accumulate via LDS atomics (8-way per address).
#pragma unroll
  for (int h = 0; h < 8; ++h) {
    int d0 = 2 * h, d1 = d0 + 1;
    int hd0 = cg + 8 * d0, hd1 = cg + 8 * d1;
    float l0 = al[hd0], l1 = al[hd1], r0 = ar[hd0], r1 = ar[hd1];
    atomicAdd(&elL[(np * 2) * 8 + h], acc0[d0] * l0 + acc0[d1] * l1);
    atomicAdd(&erL[(np * 2) * 8 + h], acc0[d0] * r0 + acc0[d1] * r1);
    atomicAdd(&elL[(np * 2 + 1) * 8 + h], acc1[d0] * l0 + acc1[d1] * l1);
    atomicAdd(&erL[(np * 2 + 1) * 8 + h], acc1[d0] * r0 + acc1[d1] * r1);
  }
  __syncthreads();
  for (int k = t; k < 512; k += 256) {
    int node = base + (k >> 3);
    if (node < n) {
      el[(size_t)node * 8 + (k & 7)] = elL[k];
      er[(size_t)node * 8 + (k & 7)] = erL[k];
    }
  }
}

// ---------------------------------------------------------------------------
// Bucket sort: coarse bucket = key >> 8. meta (uints):
// histD@0 histS@200 curbD@400 curbS@600 bktoffD@800 bktoffS@1000
// ---------------------------------------------------------------------------
__global__ __launch_bounds__(256) void k_hist(const int* __restrict__ src,
                                              const int* __restrict__ dst,
                                              unsigned* __restrict__ histD,
                                              unsigned* __restrict__ histS,
                                              int nbkt, int e) {
  __shared__ unsigned lhD[256], lhS[256];
  int t = threadIdx.x;
  lhD[t] = 0; lhS[t] = 0;
  __syncthreads();
  int base = blockIdx.x * 4096;
  for (int k = 0; k < 16; ++k) {
    int i = base + t + 256 * k;
    if (i < e) {
      atomicAdd(&lhD[((unsigned)dst[i]) >> 8], 1u);
      atomicAdd(&lhS[((unsigned)src[i]) >> 8], 1u);
    }
  }
  __syncthreads();
  if (t < nbkt) {
    if (lhD[t]) atomicAdd(&histD[t], lhD[t]);
    if (lhS[t]) atomicAdd(&histS[t], lhS[t]);
  }
}

__global__ __launch_bounds__(256) void k_bktscan(unsigned* __restrict__ meta,
                                                 unsigned* __restrict__ roffD,
                                                 unsigned* __restrict__ roffS,
                                                 int nbkt, int n, int e) {
  __shared__ unsigned s[256];
  int t = threadIdx.x;
  for (int g = 0; g < 2; ++g) {
    unsigned v = (t < nbkt) ? meta[g * 200 + t] : 0u;
    s[t] = v;
    __syncthreads();
    for (int off = 1; off < 256; off <<= 1) {
      unsigned x = (t >= off) ? s[t - off] : 0u;
      __syncthreads();
      s[t] += x;
      __syncthreads();
    }
    unsigned excl = s[t] - v;
    if (t < nbkt) {
      meta[800 + g * 200 + t] = excl;
      meta[400 + g * 200 + t] = excl;
    }
    if (t == 0) meta[800 + g * 200 + nbkt] = (unsigned)e;
    __syncthreads();
  }
  if (t == 0) { roffD[n] = (unsigned)e; roffS[n] = (unsigned)e; }
}

// Pass A: count, reserve, re-read & place (dense contiguous runs per bucket).
__global__ __launch_bounds__(256) void k_scatterA(const int* __restrict__ src,
                                                  const int* __restrict__ dst,
                                                  unsigned* __restrict__ curbD,
                                                  unsigned* __restrict__ curbS,
                                                  uint2* __restrict__ recD,
                                                  unsigned* __restrict__ recS,
                                                  int nbkt, int e) {
  __shared__ unsigned lhD[256], lhS[256], lcD[256], lcS[256];
  int t = threadIdx.x;
  lhD[t] = 0; lhS[t] = 0;
  __syncthreads();
  int base = blockIdx.x * 4096;
  for (int k = 0; k < 16; ++k) {
    int i = base + t + 256 * k;
    if (i < e) {
      atomicAdd(&lhD[((unsigned)dst[i]) >> 8], 1u);
      atomicAdd(&lhS[((unsigned)src[i]) >> 8], 1u);
    }
  }
  __syncthreads();
  if (t < nbkt) {
    lcD[t] = lhD[t] ? atomicAdd(&curbD[t], lhD[t]) : 0u;
    lcS[t] = lhS[t] ? atomicAdd(&curbS[t], lhS[t]) : 0u;
  }
  __syncthreads();
  for (int k = 0; k < 16; ++k) {
    int i = base + t + 256 * k;
    if (i < e) {
      unsigned d2 = (unsigned)dst[i], s2 = (unsigned)src[i];
      unsigned pD = atomicAdd(&lcD[d2 >> 8], 1u);
      recD[pD] = make_uint2(((d2 & 255u) << 16) | s2, (unsigned)i);
      unsigned pS = atomicAdd(&lcS[s2 >> 8], 1u);
      recS[pS] = ((s2 & 255u) << 24) | (unsigned)i;
    }
  }
}

// Pass B (dst): per-bucket fine placement + fused edge-e (leaky_relu) -> bf16 aperm.
__global__ __launch_bounds__(256) void k_finB_dst(const uint2* __restrict__ recD,
                                                  const unsigned* __restrict__ bktoff,
                                                  const float* __restrict__ el,
                                                  const float* __restrict__ er,
                                                  unsigned* __restrict__ roffD,
                                                  ushort_t* __restrict__ apermB,
                                                  int* __restrict__ srcD,
                                                  unsigned* __restrict__ eidD, int n) {
  __shared__ float erL[256 * 8];
  __shared__ unsigned cnt1[256], cnt2[256], sc[256];
  int t = threadIdx.x;
  int b = blockIdx.x;
  unsigned b0 = bktoff[b], b1 = bktoff[b + 1];
  int nb0 = b << 8;
  for (int k = 0; k < 8; ++k) {
    int idx = t + 256 * k;
    int node = nb0 + (idx >> 3);
    erL[idx] = (node < n) ? er[(size_t)nb0 * 8 + idx] : 0.f;
  }
  cnt1[t] = 0;
  __syncthreads();
  for (unsigned j = b0 + t; j < b1; j += 256) {
    unsigned nodeLoc = (recD[j].x >> 16) & 255u;
    atomicAdd(&cnt1[nodeLoc], 1u);
  }
  __syncthreads();
  unsigned v = cnt1[t];
  sc[t] = v;
  __syncthreads();
  for (int off = 1; off < 256; off <<= 1) {
    unsigned x = (t >= off) ? sc[t - off] : 0u;
    __syncthreads();
    sc[t] += x;
    __syncthreads();
  }
  unsigned excl = sc[t] - v;
  int node = nb0 + t;
  if (node < n) roffD[node] = b0 + excl;
  cnt2[t] = b0 + excl;
  __syncthreads();
  for (unsigned j = b0 + t; j < b1; j += 256) {
    uint2 r = recD[j];
    unsigned nodeLoc = (r.x >> 16) & 255u;
    unsigned srcv = r.x & 0xFFFFu;
    unsigned pos = atomicAdd(&cnt2[nodeLoc], 1u);
    float4 a0 = *(const float4*)&el[(size_t)srcv * 8];
    float4 a1 = *(const float4*)&el[(size_t)srcv * 8 + 4];
    const float* eb = &erL[nodeLoc * 8];
    float ev[8] = {a0.x + eb[0], a0.y + eb[1], a0.z + eb[2], a0.w + eb[3],
                   a1.x + eb[4], a1.y + eb[5], a1.z + eb[6], a1.w + eb[7]};
#pragma unroll
    for (int h2 = 0; h2 < 8; ++h2) ev[h2] = ev[h2] > 0.f ? ev[h2] : 0.2f * ev[h2];
    unsigned q0 = (unsigned)f2bf(ev[0]) | ((unsigned)f2bf(ev[1]) << 16);
    unsigned q1 = (unsigned)f2bf(ev[2]) | ((unsigned)f2bf(ev[3]) << 16);
    unsigned q2 = (unsigned)f2bf(ev[4]) | ((unsigned)f2bf(ev[5]) << 16);
    unsigned q3 = (unsigned)f2bf(ev[6]) | ((unsigned)f2bf(ev[7]) << 16);
    *(uint4*)&apermB[(size_t)pos * 8] = make_uint4(q0, q1, q2, q3);
    srcD[pos] = (int)srcv;
    eidD[pos] = r.y;
  }
}

// Pass B (src): payload = orig edge id.
__global__ __launch_bounds__(256) void k_finB_src(const unsigned* __restrict__ recS,
                                                  const unsigned* __restrict__ bktoff,
                                                  unsigned* __restrict__ roffS,
                                                  unsigned* __restrict__ eidS, int n) {
  __shared__ unsigned cnt1[256], cnt2[256], sc[256];
  int t = threadIdx.x;
  int b = blockIdx.x;
  unsigned b0 = bktoff[b], b1 = bktoff[b + 1];
  int nb0 = b << 8;
  cnt1[t] = 0;
  __syncthreads();
  for (unsigned j = b0 + t; j < b1; j += 256) {
    unsigned nodeLoc = recS[j] >> 24;
    atomicAdd(&cnt1[nodeLoc], 1u);
  }
  __syncthreads();
  unsigned v = cnt1[t];
  sc[t] = v;
  __syncthreads();
  for (int off = 1; off < 256; off <<= 1) {
    unsigned x = (t >= off) ? sc[t - off] : 0u;
    __syncthreads();
    sc[t] += x;
    __syncthreads();
  }
  unsigned excl = sc[t] - v;
  int node = nb0 + t;
  if (node < n) roffS[node] = b0 + excl;
  cnt2[t] = b0 + excl;
  __syncthreads();
  for (unsigned j = b0 + t; j < b1; j += 256) {
    unsigned r = recS[j];
    unsigned nodeLoc = r >> 24;
    unsigned pos = atomicAdd(&cnt2[nodeLoc], 1u);
    eidS[pos] = r & 0x00FFFFFFu;
  }
}

// ---------------------------------------------------------------------------
// K-attn (fused): per 32-node group, stage segment in LDS:
// softmax (in LDS) -> dst-half sum_w via per-(node,h) MLP walk -> one per-edge
// pass writing normalized bf16 apermB + scattered fp32 attn. Fallback to a
// global-memory path if the group's segment exceeds SEGCAP.
// ---------------------------------------------------------------------------
__global__ __launch_bounds__(256) void k_attn(const unsigned* __restrict__ roffD,
                                              const unsigned* __restrict__ eidD,
                                              ushort_t* __restrict__ apermB,
                                              const float* __restrict__ aw1,
                                              const float* __restrict__ ab1,
                                              const float* __restrict__ aw2,
                                              const float* __restrict__ ab2,
                                              float* __restrict__ attn,
                                              float* __restrict__ swD, int n) {
  __shared__ float aL[SEGCAP * 8];
  __shared__ float W1[64], W2[64], B1[8], B2[8];
  __shared__ unsigned nb_[33];
  int t = threadIdx.x;
  if (t < 64) { W1[t] = aw1[t]; W2[t] = aw2[t]; }
  else if (t < 72) { B1[t - 64] = ab1[t - 64]; B2[t - 64] = ab2[t - 64]; }
  int g0 = blockIdx.x * 32;
  if (t < 33) {
    int node = g0 + t;
    nb_[t] = roffD[node < n ? node : n];
  }
  __syncthreads();
  unsigned b0 = nb_[0], b1 = nb_[32];
  unsigned count = b1 - b0;
  int ln = t >> 3, h = t & 7;
  int node = g0 + ln;
  if (count <= SEGCAP) {
    // ---- fast path ----
    const unsigned* ap32 = (const unsigned*)apermB + (size_t)b0 * 4;
    for (unsigned k = t; k < count * 4; k += 256) {
      unsigned pk = ap32[k];
      aL[k * 2] = bf2f((ushort_t)(pk & 0xFFFFu));
      aL[k * 2 + 1] = bf2f((ushort_t)(pk >> 16));
    }
    __syncthreads();
    unsigned s0 = nb_[ln] - b0, s1 = nb_[ln + 1] - b0;
    if (node < n) {
      float s = 0.f;
      for (unsigned j = s0; j < s1; ++j) {
        float ex = expf(aL[j * 8 + h]);
        aL[j * 8 + h] = ex;
        s += ex;
      }
      float inv = s > 0.f ? 1.f / s : 0.f;
      for (unsigned j = s0; j < s1; ++j) aL[j * 8 + h] *= inv;
    }
    __syncthreads();
    // dst-half sum_w: per-(node,h) walk, full tiny MLP per edge (VALU idle)
    if (node < n) {
      float s = 0.f;
      for (unsigned j = s0; j < s1; ++j) {
        const float* a = &aL[j * 8];
        float w = B2[h];
#pragma unroll
        for (int kk = 0; kk < 8; ++kk) {
          float acc = B1[kk];
#pragma unroll
          for (int m = 0; m < 8; ++m) acc += a[m] * W1[kk * 8 + m];
          acc = acc > 0.f ? acc : 0.f;
          w += acc * W2[h * 8 + kk];
        }
        s += 1.f - w;
      }
      swD[(size_t)node * 8 + h] = s;
    }
    // per-edge writeback: normalized bf16 apermB (coalesced) + attn scatter
    for (unsigned eL = t; eL < count; eL += 256) {
      const float* a = &aL[eL * 8];
      unsigned ee = eidD[b0 + eL];
      float4* op = (float4*)&attn[(size_t)ee * 8];
      op[0] = make_float4(a[0], a[1], a[2], a[3]);
      op[1] = make_float4(a[4], a[5], a[6], a[7]);
      unsigned q0 = (unsigned)f2bf(a[0]) | ((unsigned)f2bf(a[1]) << 16);
      unsigned q1 = (unsigned)f2bf(a[2]) | ((unsigned)f2bf(a[3]) << 16);
      unsigned q2 = (unsigned)f2bf(a[4]) | ((unsigned)f2bf(a[5]) << 16);
      unsigned q3 = (unsigned)f2bf(a[6]) | ((unsigned)f2bf(a[7]) << 16);
      *(uint4*)&apermB[(size_t)(b0 + eL) * 8] = make_uint4(q0, q1, q2, q3);
    }
  } else {
    // ---- slow path (global, correctness-only; essentially never taken) ----
    unsigned sb = nb_[ln], se = nb_[ln + 1];
    if (node < n) {
      float s = 0.f;
      for (unsigned j = sb; j < se; ++j) s += expf(bf2f(apermB[(size_t)j * 8 + h]));
      float inv = s > 0.f ? 1.f / s : 0.f;
      for (unsigned j = sb; j < se; ++j) {
        size_t p = (size_t)j * 8 + h;
        apermB[p] = f2bf(expf(bf2f(apermB[p])) * inv);
      }
    }
    __syncthreads();
    if (node < n) {
      float s = 0.f;
      for (unsigned j = sb; j < se; ++j) {
        float a[8];
#pragma unroll
        for (int m = 0; m < 8; ++m) a[m] = bf2f(apermB[(size_t)j * 8 + m]);
        float w = B2[h];
#pragma unroll
        for (int kk = 0; kk < 8; ++kk) {
          float acc = B1[kk];
#pragma unroll
          for (int m = 0; m < 8; ++m) acc += a[m] * W1[kk * 8 + m];
          acc = acc > 0.f ? acc : 0.f;
          w += acc * W2[h * 8 + kk];
        }
        s += 1.f - w;
      }
      swD[(size_t)node * 8 + h] = s;
    }
    for (unsigned eL = t; eL < count; eL += 256) {
      unsigned j = b0 + eL;
      float a[8];
#pragma unroll
      for (int m = 0; m < 8; ++m) a[m] = bf2f(apermB[(size_t)j * 8 + m]);
      unsigned ee = eidD[j];
      float4* op = (float4*)&attn[(size_t)ee * 8];
      op[0] = make_float4(a[0], a[1], a[2], a[3]);
      op[1] = make_float4(a[4], a[5], a[6], a[7]);
    }
  }
}

// K5: sum_w = swD + src-half (gather attn row by orig eid + recompute MLP) -> t_relu.
__global__ __launch_bounds__(256) void k_sumw_tr(const unsigned* __restrict__ roffS,
                                                 const unsigned* __restrict__ eidS,
                                                 const float* __restrict__ swD,
                                                 const float* __restrict__ attn,
                                                 const float* __restrict__ aw1,
                                                 const float* __restrict__ ab1,
                                                 const float* __restrict__ aw2,
                                                 const float* __restrict__ ab2,
                                                 const float* __restrict__ tw1,
                                                 const float* __restrict__ tb1,
                                                 float* __restrict__ tr, int n) {
  __shared__ float sw[32][9];
  __shared__ float W1[64], W2[64], B1[8], B2[8];
  int t = threadIdx.x;
  if (t < 64) { W1[t] = aw1[t]; W2[t] = aw2[t]; }
  else if (t < 72) { B1[t - 64] = ab1[t - 64]; B2[t - 64] = ab2[t - 64]; }
  __syncthreads();
  int ln = t >> 3, h = t & 7;
  int node = blockIdx.x * 32 + ln;
  if (node < n) {
    float s = swD[(size_t)node * 8 + h];
    unsigned b = roffS[node], en = roffS[node + 1];
    for (unsigned j = b; j < en; ++j) {
      unsigned eid = eidS[j];
      float4 a0 = *(const float4*)&attn[(size_t)eid * 8];
      float4 a1 = *(const float4*)&attn[(size_t)eid * 8 + 4];
      float a[8] = {a0.x, a0.y, a0.z, a0.w, a1.x, a1.y, a1.z, a1.w};
      float w = B2[h];
#pragma unroll
      for (int kk = 0; kk < 8; ++kk) {
        float acc = B1[kk];
#pragma unroll
        for (int m = 0; m < 8; ++m) acc += a[m] * W1[kk * 8 + m];
        acc = acc > 0.f ? acc : 0.f;
        w += acc * W2[h * 8 + kk];
      }
      s += 1.f - w;
    }
    sw[ln][h] = s;
  }
  __syncthreads();
  if (node < n) {
    const float* wv = &tw1[h * 8];
    float acc = tb1[h];
#pragma unroll
    for (int kk = 0; kk < 8; ++kk) acc += sw[ln][kk] * wv[kk];
    tr[(size_t)node * 8 + h] = acc > 0.f ? acc : 0.f;
  }
}

// K-msg (fused e_emb + BN stats): wave handles 4 nodes; lane owns 2 bf16
// features; 4-edge unroll for memory-level parallelism.
__global__ __launch_bounds__(256) void k_msg(const int* __restrict__ srcD,
                                             const unsigned* __restrict__ roff,
                                             const ushort_t* __restrict__ apermB,
                                             const ushort_t* __restrict__ featbf,
                                             const float* __restrict__ tr,
                                             const float* __restrict__ tw2,
                                             const float* __restrict__ tb2,
                                             const float* __restrict__ gat_bias,
                                             float* __restrict__ hout,
                                             float* __restrict__ partial, int n) {
  __shared__ float bn1[4][128], bn2[4][128];
  int t = threadIdx.x;
  int w = t >> 6, lane = t & 63;
  int col = lane * 2;
  int hh = lane >> 3;
  float w2a[8], w2b[8];
#pragma unroll
  for (int j = 0; j < 8; ++j) { w2a[j] = tw2[col * 8 + j]; w2b[j] = tw2[(col + 1) * 8 + j]; }
  float biasA = tb2[col] + gat_bias[col];
  float biasB = tb2[col + 1] + gat_bias[col + 1];
  float s1a = 0.f, s1b = 0.f, s2a = 0.f, s2b = 0.f;
  int nodeBase = blockIdx.x * 16 + w * 4;
  for (int ni = 0; ni < 4; ++ni) {
    int node = nodeBase + ni;
    if (node >= n) break;
    unsigned b = roff[node], en = roff[node + 1];
    float x0 = 0.f, x1 = 0.f;
    unsigned j = b;
    for (; j + 4 <= en; j += 4) {
      int sa = srcD[j], sb = srcD[j + 1], sc2 = srcD[j + 2], sd = srcD[j + 3];
      float av0 = bf2f(apermB[(size_t)j * 8 + hh]);
      float av1 = bf2f(apermB[(size_t)(j + 1) * 8 + hh]);
      float av2 = bf2f(apermB[(size_t)(j + 2) * 8 + hh]);
      float av3 = bf2f(apermB[(size_t)(j + 3) * 8 + hh]);
      unsigned p0 = *(const unsigned*)&featbf[(size_t)sa * 128 + col];
      unsigned p1 = *(const unsigned*)&featbf[(size_t)sb * 128 + col];
      unsigned p2 = *(const unsigned*)&featbf[(size_t)sc2 * 128 + col];
      unsigned p3 = *(const unsigned*)&featbf[(size_t)sd * 128 + col];
      x0 += bf2f((ushort_t)(p0 & 0xFFFFu)) * av0 + bf2f((ushort_t)(p1 & 0xFFFFu)) * av1 +
            bf2f((ushort_t)(p2 & 0xFFFFu)) * av2 + bf2f((ushort_t)(p3 & 0xFFFFu)) * av3;
      x1 += bf2f((ushort_t)(p0 >> 16)) * av0 + bf2f((ushort_t)(p1 >> 16)) * av1 +
            bf2f((ushort_t)(p2 >> 16)) * av2 + bf2f((ushort_t)(p3 >> 16)) * av3;
    }
    for (; j < en; ++j) {
      int sa = srcD[j];
      float av0 = bf2f(apermB[(size_t)j * 8 + hh]);
      unsigned p0 = *(const unsigned*)&featbf[(size_t)sa * 128 + col];
      x0 += bf2f((ushort_t)(p0 & 0xFFFFu)) * av0;
      x1 += bf2f((ushort_t)(p0 >> 16)) * av0;
    }
    const float* trn = &tr[(size_t)node * 8];
    float emA = biasA, emB = biasB;
#pragma unroll
    for (int jj = 0; jj < 8; ++jj) {
      float tv = trn[jj];
      emA += tv * w2a[jj];
      emB += tv * w2b[jj];
    }
    float v0 = x0 + emA, v1 = x1 + emB;
    *(float2*)&hout[(size_t)node * 128 + col] = make_float2(v0, v1);
    s1a += v0; s1b += v1; s2a += v0 * v0; s2b += v1 * v1;
  }
  bn1[w][col] = s1a; bn1[w][col + 1] = s1b;
  bn2[w][col] = s2a; bn2[w][col + 1] = s2b;
  __syncthreads();
  int f = t & 127;
  float acc;
  if (t < 128) acc = bn1[0][f] + bn1[1][f] + bn1[2][f] + bn1[3][f];
  else         acc = bn2[0][f] + bn2[1][f] + bn2[2][f] + bn2[3][f];
  partial[(size_t)blockIdx.x * 256 + t] = acc;
}

// Reduce per-block BN partials.
__global__ __launch_bounds__(256) void k_red(const float* __restrict__ partial,
                                             float* __restrict__ bnacc, int rows) {
  int t = threadIdx.x;
  int r0 = blockIdx.x * 13, r1 = r0 + 13;
  if (r1 > rows) r1 = rows;
  if (r0 >= r1) return;
  float acc = 0.f;
  for (int r = r0; r < r1; ++r) acc += partial[(size_t)r * 256 + t];
  atomicAdd(&bnacc[t], acc);
}

__global__ void k_bnfin(const float* __restrict__ bnsum, const float* __restrict__ bnsq,
                        const float* __restrict__ gamma, float* __restrict__ mu,
                        float* __restrict__ scale, int n) {
  int i = threadIdx.x;
  if (i < 128) {
    float m = bnsum[i] / (float)n;
    float v = bnsq[i] / (float)n - m * m;
    mu[i] = m;
    scale[i] = rsqrtf(v + 1e-5f) * gamma[i];
  }
}

// K7: out = h_in + elu((x - mu)*scale + beta)
__global__ void k_final(const float* __restrict__ hin, float* __restrict__ hout,
                        const float* __restrict__ mu, const float* __restrict__ scale,
                        const float* __restrict__ beta, int total4) {
  int i = blockIdx.x * blockDim.x + threadIdx.x;
  if (i >= total4) return;
  int c = (i & 31) * 4;
  float4 x = ((const float4*)hout)[i];
  float4 m4 = *(const float4*)&mu[c];
  float4 s4 = *(const float4*)&scale[c];
  float4 b4 = *(const float4*)&beta[c];
  float4 hi = ((const float4*)hin)[i];
  float y0 = (x.x - m4.x) * s4.x + b4.x;
  float y1 = (x.y - m4.y) * s4.y + b4.y;
  float y2 = (x.z - m4.z) * s4.z + b4.z;
  float y3 = (x.w - m4.w) * s4.w + b4.w;
  y0 = y0 > 0.f ? y0 : expm1f(y0);
  y1 = y1 > 0.f ? y1 : expm1f(y1);
  y2 = y2 > 0.f ? y2 : expm1f(y2);
  y3 = y3 > 0.f ? y3 : expm1f(y3);
  float4 o = make_float4(hi.x + y0, hi.y + y1, hi.z + y2, hi.w + y3);
  ((float4*)hout)[i] = o;
}

extern "C" void kernel_launch(void* const* d_in, const int* in_sizes, int n_in,
                              void* d_out, int out_size, void* d_ws, size_t ws_size,
                              hipStream_t stream) {
  const float* h_in     = (const float*)d_in[0];
  const int*   esrc     = (const int*)d_in[1];
  const int*   edst     = (const int*)d_in[2];
  const float* fc_w     = (const float*)d_in[4];
  const float* attn_l   = (const float*)d_in[5];
  const float* attn_r   = (const float*)d_in[6];
  const float* gat_bias = (const float*)d_in[7];
  const float* aw1      = (const float*)d_in[8];
  const float* ab1      = (const float*)d_in[9];
  const float* aw2      = (const float*)d_in[10];
  const float* ab2      = (const float*)d_in[11];
  const float* tw1      = (const float*)d_in[12];
  const float* tb1      = (const float*)d_in[13];
  const float* tw2      = (const float*)d_in[14];
  const float* tb2      = (const float*)d_in[15];
  const float* gamma    = (const float*)d_in[16];
  const float* beta     = (const float*)d_in[17];

  const int n = in_sizes[0] / 128;  // 50000
  const int e = in_sizes[1];        // 600000
  const int nbkt = CDIV(n, 256);    // 196
  const int gridMsg = CDIV(n, 16);  // 3125

  float* ws = (float*)d_ws;
  size_t OFF_FEAT  = 0;                          // n*128 ushorts = n*64 floats
  size_t OFF_EL    = OFF_FEAT + (size_t)n * 64;
  size_t OFF_ER    = OFF_EL + (size_t)n * 8;
  size_t OFF_ROFD  = OFF_ER + (size_t)n * 8;
  size_t OFF_ROFS  = OFF_ROFD + (size_t)(n + 16);
  size_t OFF_EIDD  = OFF_ROFS + (size_t)(n + 16);
  size_t OFF_SRCD  = OFF_EIDD + (size_t)e;
  size_t OFF_EIDS  = OFF_SRCD + (size_t)e;
  size_t OFF_APERM = OFF_EIDS + (size_t)e;       // bf16: e*8 ushorts = e*4 floats
  size_t OFF_PART  = OFF_APERM + (size_t)e * 4;
  size_t OFF_META  = OFF_PART + (size_t)gridMsg * 256;
  size_t OFF_BN    = OFF_META + 1200;

  ushort_t* featbf = (ushort_t*)(ws + OFF_FEAT);
  float*    el     = ws + OFF_EL;
  float*    er     = ws + OFF_ER;
  unsigned* roffD  = (unsigned*)(ws + OFF_ROFD);
  unsigned* roffS  = (unsigned*)(ws + OFF_ROFS);
  unsigned* eidD   = (unsigned*)(ws + OFF_EIDD);
  int*      srcD   = (int*)(ws + OFF_SRCD);
  unsigned* eidS   = (unsigned*)(ws + OFF_EIDS);
  ushort_t* apermB = (ushort_t*)(ws + OFF_APERM);
  float*    partial= ws + OFF_PART;
  unsigned* meta   = (unsigned*)(ws + OFF_META);
  float*    bnsum  = ws + OFF_BN;
  float*    bnsq   = bnsum + 128;
  float*    mu     = bnsum + 256;
  float*    scale  = bnsum + 384;
  float*    tr     = el;  // alias: el dead after k_finB_dst
  float*    swD    = er;  // alias: er dead after k_finB_dst

  float* hout = (float*)d_out;
  float* attn = (float*)d_out + (size_t)n * 128;
  uint2*    recD = (uint2*)attn;                          // dead once k_attn writes attn
  unsigned* recS = (unsigned*)(attn + (size_t)e * 2);

  hipMemsetAsync(meta, 0, 400 * sizeof(unsigned), stream);   // histD+histS
  hipMemsetAsync(bnsum, 0, 256 * sizeof(float), stream);
  size_t head = (size_t)n * 128 + (size_t)e * 8;
  if ((size_t)out_size > head)
    hipMemsetAsync((float*)d_out + head, 0, ((size_t)out_size - head) * sizeof(float), stream);

  k_gemm<<<CDIV(n, 64), 256, 0, stream>>>(h_in, fc_w, attn_l, attn_r, featbf, el, er, n);

  // bucket sort (both graphs)
  k_hist<<<CDIV(e, 4096), 256, 0, stream>>>(esrc, edst, meta, meta + 200, nbkt, e);
  k_bktscan<<<1, 256, 0, stream>>>(meta, roffD, roffS, nbkt, n, e);
  k_scatterA<<<CDIV(e, 4096), 256, 0, stream>>>(esrc, edst, meta + 400, meta + 600,
                                                recD, recS, nbkt, e);
  k_finB_dst<<<nbkt, 256, 0, stream>>>(recD, meta + 800, el, er, roffD, apermB, srcD,
                                       eidD, n);
  k_finB_src<<<nbkt, 256, 0, stream>>>(recS, meta + 1000, roffS, eidS, n);

  // fused softmax + edge MLP + dst-sum_w + attn writeback
  k_attn<<<CDIV(n, 32), 256, 0, stream>>>(roffD, eidD, apermB, aw1, ab1, aw2, ab2,
                                          attn, swD, n);
  k_sumw_tr<<<CDIV(n, 32), 256, 0, stream>>>(roffS, eidS, swD, attn, aw1, ab1, aw2, ab2,
                                             tw1, tb1, tr, n);

  // message aggregation + e_emb + BN partials
  k_msg<<<gridMsg, 256, 0, stream>>>(srcD, roffD, apermB, featbf, tr, tw2, tb2, gat_bias,
                                     hout, partial, n);
  k_red<<<CDIV(gridMsg, 13), 256, 0, stream>>>(partial, bnsum, gridMsg);
  k_bnfin<<<1, 128, 0, stream>>>(bnsum, bnsq, gamma, mu, scale, n);
  k_final<<<CDIV(n * 32, 256), 256, 0, stream>>>(h_in, hout, mu, scale, beta, n * 32);
}

// Round 7
// 351.695 us; speedup vs baseline: 1.1320x; 1.1320x over previous
//
#include <hip/hip_runtime.h>
#include <math.h>

#define CDIV(a,b) (((a)+(b)-1)/(b))
#define SEGCAP 768  // max edges per 32-node group in LDS fast path (mean 384)

typedef unsigned short ushort_t;

__device__ __forceinline__ ushort_t f2bf(float x) {
  unsigned u = __float_as_uint(x);
  unsigned r = (u + 0x7FFFu + ((u >> 16) & 1u)) >> 16;
  return (ushort_t)r;
}
__device__ __forceinline__ float bf2f(ushort_t s) {
  return __uint_as_float(((unsigned)s) << 16);
}

// ---------------------------------------------------------------------------
// K1: feat = h @ fc_w.T (N x 128) -> bf16; fused el/er epilogue via wave
// shuffles (8-lane butterfly over cg) -- no LDS atomics (round-6 regression).
// ---------------------------------------------------------------------------
__global__ __launch_bounds__(256) void k_gemm(const float* __restrict__ hm,
                                              const float* __restrict__ w,
                                              const float* __restrict__ al,
                                              const float* __restrict__ ar,
                                              ushort_t* __restrict__ featbf,
                                              float* __restrict__ el,
                                              float* __restrict__ er, int n) {
  __shared__ float wl[128 * 68];
  __shared__ float hl[64 * 68];
  const int t = threadIdx.x;
  const int base = blockIdx.x * 64;
  const int cg = t & 7;
  const int np = t >> 3;
  float acc0[16], acc1[16];
#pragma unroll
  for (int d = 0; d < 16; ++d) { acc0[d] = 0.f; acc1[d] = 0.f; }

  for (int half = 0; half < 2; ++half) {
    const int k0q = half * 16;
    if (half) __syncthreads();
    for (int r = 0; r < 8; ++r) {
      int f = t + 256 * r;
      int row = f >> 4, c4 = f & 15;
      float4 v = ((const float4*)w)[row * 32 + k0q + c4];
      float* dp = &wl[row * 68 + c4 * 4];
      dp[0] = v.x; dp[1] = v.y; dp[2] = v.z; dp[3] = v.w;
    }
    for (int r = 0; r < 4; ++r) {
      int f = t + 256 * r;
      int row = f >> 4, c4 = f & 15;
      int nidx = base + row;
      float4 v = make_float4(0.f, 0.f, 0.f, 0.f);
      if (nidx < n) v = ((const float4*)hm)[nidx * 32 + k0q + c4];
      float* dp = &hl[row * 68 + c4 * 4];
      dp[0] = v.x; dp[1] = v.y; dp[2] = v.z; dp[3] = v.w;
    }
    __syncthreads();
    const float* h0 = &hl[(np * 2) * 68];
    const float* h1 = &hl[(np * 2 + 1) * 68];
    for (int c = 0; c < 16; ++c) {
      int k = c * 4;
      float4 a0 = *(const float4*)&h0[k];
      float4 a1 = *(const float4*)&h1[k];
#pragma unroll
      for (int d = 0; d < 16; ++d) {
        float4 wv = *(const float4*)&wl[(cg + 8 * d) * 68 + k];
        acc0[d] += a0.x * wv.x + a0.y * wv.y + a0.z * wv.z + a0.w * wv.w;
        acc1[d] += a1.x * wv.x + a1.y * wv.y + a1.z * wv.z + a1.w * wv.w;
      }
    }
  }
  int n0 = base + np * 2, n1 = n0 + 1;
  if (n0 < n) {
#pragma unroll
    for (int d = 0; d < 16; ++d) featbf[(size_t)n0 * 128 + cg + 8 * d] = f2bf(acc0[d]);
  }
  if (n1 < n) {
#pragma unroll
    for (int d = 0; d < 16; ++d) featbf[(size_t)n1 * 128 + cg + 8 * d] = f2bf(acc1[d]);
  }
  // ---- fused el/er: head h needs d=2h,2h+1 from every cg lane; butterfly
  // over the 8 consecutive cg lanes, lane cg==h writes. ----
#pragma unroll
  for (int h = 0; h < 8; ++h) {
    int d0 = 2 * h, d1 = d0 + 1;
    int hd0 = cg + 8 * d0, hd1 = cg + 8 * d1;
    float l0 = al[hd0], l1 = al[hd1], r0 = ar[hd0], r1 = ar[hd1];
    float pl0 = acc0[d0] * l0 + acc0[d1] * l1;
    float pr0 = acc0[d0] * r0 + acc0[d1] * r1;
    float pl1 = acc1[d0] * l0 + acc1[d1] * l1;
    float pr1 = acc1[d0] * r0 + acc1[d1] * r1;
#pragma unroll
    for (int off = 1; off < 8; off <<= 1) {
      pl0 += __shfl_xor(pl0, off);
      pr0 += __shfl_xor(pr0, off);
      pl1 += __shfl_xor(pl1, off);
      pr1 += __shfl_xor(pr1, off);
    }
    if (cg == h) {
      if (n0 < n) { el[(size_t)n0 * 8 + h] = pl0; er[(size_t)n0 * 8 + h] = pr0; }
      if (n1 < n) { el[(size_t)n1 * 8 + h] = pl1; er[(size_t)n1 * 8 + h] = pr1; }
    }
  }
}

// ---------------------------------------------------------------------------
// Bucket sort: coarse bucket = key >> 8. meta (uints):
// histD@0 histS@200 curbD@400 curbS@600 bktoffD@800 bktoffS@1000
// ---------------------------------------------------------------------------
__global__ __launch_bounds__(256) void k_hist(const int* __restrict__ src,
                                              const int* __restrict__ dst,
                                              unsigned* __restrict__ histD,
                                              unsigned* __restrict__ histS,
                                              int nbkt, int e) {
  __shared__ unsigned lhD[256], lhS[256];
  int t = threadIdx.x;
  lhD[t] = 0; lhS[t] = 0;
  __syncthreads();
  int base = blockIdx.x * 4096;
  for (int k = 0; k < 16; ++k) {
    int i = base + t + 256 * k;
    if (i < e) {
      atomicAdd(&lhD[((unsigned)dst[i]) >> 8], 1u);
      atomicAdd(&lhS[((unsigned)src[i]) >> 8], 1u);
    }
  }
  __syncthreads();
  if (t < nbkt) {
    if (lhD[t]) atomicAdd(&histD[t], lhD[t]);
    if (lhS[t]) atomicAdd(&histS[t], lhS[t]);
  }
}

__global__ __launch_bounds__(256) void k_bktscan(unsigned* __restrict__ meta,
                                                 unsigned* __restrict__ roffD,
                                                 unsigned* __restrict__ roffS,
                                                 int nbkt, int n, int e) {
  __shared__ unsigned s[256];
  int t = threadIdx.x;
  for (int g = 0; g < 2; ++g) {
    unsigned v = (t < nbkt) ? meta[g * 200 + t] : 0u;
    s[t] = v;
    __syncthreads();
    for (int off = 1; off < 256; off <<= 1) {
      unsigned x = (t >= off) ? s[t - off] : 0u;
      __syncthreads();
      s[t] += x;
      __syncthreads();
    }
    unsigned excl = s[t] - v;
    if (t < nbkt) {
      meta[800 + g * 200 + t] = excl;
      meta[400 + g * 200 + t] = excl;
    }
    if (t == 0) meta[800 + g * 200 + nbkt] = (unsigned)e;
    __syncthreads();
  }
  if (t == 0) { roffD[n] = (unsigned)e; roffS[n] = (unsigned)e; }
}

// Pass A: count, reserve, re-read & place (dense contiguous runs per bucket).
__global__ __launch_bounds__(256) void k_scatterA(const int* __restrict__ src,
                                                  const int* __restrict__ dst,
                                                  unsigned* __restrict__ curbD,
                                                  unsigned* __restrict__ curbS,
                                                  uint2* __restrict__ recD,
                                                  unsigned* __restrict__ recS,
                                                  int nbkt, int e) {
  __shared__ unsigned lhD[256], lhS[256], lcD[256], lcS[256];
  int t = threadIdx.x;
  lhD[t] = 0; lhS[t] = 0;
  __syncthreads();
  int base = blockIdx.x * 4096;
  for (int k = 0; k < 16; ++k) {
    int i = base + t + 256 * k;
    if (i < e) {
      atomicAdd(&lhD[((unsigned)dst[i]) >> 8], 1u);
      atomicAdd(&lhS[((unsigned)src[i]) >> 8], 1u);
    }
  }
  __syncthreads();
  if (t < nbkt) {
    lcD[t] = lhD[t] ? atomicAdd(&curbD[t], lhD[t]) : 0u;
    lcS[t] = lhS[t] ? atomicAdd(&curbS[t], lhS[t]) : 0u;
  }
  __syncthreads();
  for (int k = 0; k < 16; ++k) {
    int i = base + t + 256 * k;
    if (i < e) {
      unsigned d2 = (unsigned)dst[i], s2 = (unsigned)src[i];
      unsigned pD = atomicAdd(&lcD[d2 >> 8], 1u);
      recD[pD] = make_uint2(((d2 & 255u) << 16) | s2, (unsigned)i);
      unsigned pS = atomicAdd(&lcS[s2 >> 8], 1u);
      recS[pS] = ((s2 & 255u) << 24) | (unsigned)i;
    }
  }
}

// Pass B (dst): per-bucket fine placement + fused edge-e (leaky_relu) -> bf16 aperm.
__global__ __launch_bounds__(256) void k_finB_dst(const uint2* __restrict__ recD,
                                                  const unsigned* __restrict__ bktoff,
                                                  const float* __restrict__ el,
                                                  const float* __restrict__ er,
                                                  unsigned* __restrict__ roffD,
                                                  ushort_t* __restrict__ apermB,
                                                  int* __restrict__ srcD,
                                                  unsigned* __restrict__ eidD, int n) {
  __shared__ float erL[256 * 8];
  __shared__ unsigned cnt1[256], cnt2[256], sc[256];
  int t = threadIdx.x;
  int b = blockIdx.x;
  unsigned b0 = bktoff[b], b1 = bktoff[b + 1];
  int nb0 = b << 8;
  for (int k = 0; k < 8; ++k) {
    int idx = t + 256 * k;
    int node = nb0 + (idx >> 3);
    erL[idx] = (node < n) ? er[(size_t)nb0 * 8 + idx] : 0.f;
  }
  cnt1[t] = 0;
  __syncthreads();
  for (unsigned j = b0 + t; j < b1; j += 256) {
    unsigned nodeLoc = (recD[j].x >> 16) & 255u;
    atomicAdd(&cnt1[nodeLoc], 1u);
  }
  __syncthreads();
  unsigned v = cnt1[t];
  sc[t] = v;
  __syncthreads();
  for (int off = 1; off < 256; off <<= 1) {
    unsigned x = (t >= off) ? sc[t - off] : 0u;
    __syncthreads();
    sc[t] += x;
    __syncthreads();
  }
  unsigned excl = sc[t] - v;
  int node = nb0 + t;
  if (node < n) roffD[node] = b0 + excl;
  cnt2[t] = b0 + excl;
  __syncthreads();
  for (unsigned j = b0 + t; j < b1; j += 256) {
    uint2 r = recD[j];
    unsigned nodeLoc = (r.x >> 16) & 255u;
    unsigned srcv = r.x & 0xFFFFu;
    unsigned pos = atomicAdd(&cnt2[nodeLoc], 1u);
    float4 a0 = *(const float4*)&el[(size_t)srcv * 8];
    float4 a1 = *(const float4*)&el[(size_t)srcv * 8 + 4];
    const float* eb = &erL[nodeLoc * 8];
    float ev[8] = {a0.x + eb[0], a0.y + eb[1], a0.z + eb[2], a0.w + eb[3],
                   a1.x + eb[4], a1.y + eb[5], a1.z + eb[6], a1.w + eb[7]};
#pragma unroll
    for (int h2 = 0; h2 < 8; ++h2) ev[h2] = ev[h2] > 0.f ? ev[h2] : 0.2f * ev[h2];
    unsigned q0 = (unsigned)f2bf(ev[0]) | ((unsigned)f2bf(ev[1]) << 16);
    unsigned q1 = (unsigned)f2bf(ev[2]) | ((unsigned)f2bf(ev[3]) << 16);
    unsigned q2 = (unsigned)f2bf(ev[4]) | ((unsigned)f2bf(ev[5]) << 16);
    unsigned q3 = (unsigned)f2bf(ev[6]) | ((unsigned)f2bf(ev[7]) << 16);
    *(uint4*)&apermB[(size_t)pos * 8] = make_uint4(q0, q1, q2, q3);
    srcD[pos] = (int)srcv;
    eidD[pos] = r.y;
  }
}

// Pass B (src): payload = orig edge id.
__global__ __launch_bounds__(256) void k_finB_src(const unsigned* __restrict__ recS,
                                                  const unsigned* __restrict__ bktoff,
                                                  unsigned* __restrict__ roffS,
                                                  unsigned* __restrict__ eidS, int n) {
  __shared__ unsigned cnt1[256], cnt2[256], sc[256];
  int t = threadIdx.x;
  int b = blockIdx.x;
  unsigned b0 = bktoff[b], b1 = bktoff[b + 1];
  int nb0 = b << 8;
  cnt1[t] = 0;
  __syncthreads();
  for (unsigned j = b0 + t; j < b1; j += 256) {
    unsigned nodeLoc = recS[j] >> 24;
    atomicAdd(&cnt1[nodeLoc], 1u);
  }
  __syncthreads();
  unsigned v = cnt1[t];
  sc[t] = v;
  __syncthreads();
  for (int off = 1; off < 256; off <<= 1) {
    unsigned x = (t >= off) ? sc[t - off] : 0u;
    __syncthreads();
    sc[t] += x;
    __syncthreads();
  }
  unsigned excl = sc[t] - v;
  int node = nb0 + t;
  if (node < n) roffS[node] = b0 + excl;
  cnt2[t] = b0 + excl;
  __syncthreads();
  for (unsigned j = b0 + t; j < b1; j += 256) {
    unsigned r = recS[j];
    unsigned nodeLoc = r >> 24;
    unsigned pos = atomicAdd(&cnt2[nodeLoc], 1u);
    eidS[pos] = r & 0x00FFFFFFu;
  }
}

// ---------------------------------------------------------------------------
// K-attn (fused): per 32-node group, stage segment in LDS: softmax -> dst-half
// sum_w via per-(node,h) MLP walk -> per-edge writeback (bf16 apermB + attn).
// ---------------------------------------------------------------------------
__global__ __launch_bounds__(256) void k_attn(const unsigned* __restrict__ roffD,
                                              const unsigned* __restrict__ eidD,
                                              ushort_t* __restrict__ apermB,
                                              const float* __restrict__ aw1,
                                              const float* __restrict__ ab1,
                                              const float* __restrict__ aw2,
                                              const float* __restrict__ ab2,
                                              float* __restrict__ attn,
                                              float* __restrict__ swD, int n) {
  __shared__ float aL[SEGCAP * 8];
  __shared__ float W1[64], W2[64], B1[8], B2[8];
  __shared__ unsigned nb_[33];
  int t = threadIdx.x;
  if (t < 64) { W1[t] = aw1[t]; W2[t] = aw2[t]; }
  else if (t < 72) { B1[t - 64] = ab1[t - 64]; B2[t - 64] = ab2[t - 64]; }
  int g0 = blockIdx.x * 32;
  if (t < 33) {
    int node = g0 + t;
    nb_[t] = roffD[node < n ? node : n];
  }
  __syncthreads();
  unsigned b0 = nb_[0], b1 = nb_[32];
  unsigned count = b1 - b0;
  int ln = t >> 3, h = t & 7;
  int node = g0 + ln;
  if (count <= SEGCAP) {
    const unsigned* ap32 = (const unsigned*)apermB + (size_t)b0 * 4;
    for (unsigned k = t; k < count * 4; k += 256) {
      unsigned pk = ap32[k];
      aL[k * 2] = bf2f((ushort_t)(pk & 0xFFFFu));
      aL[k * 2 + 1] = bf2f((ushort_t)(pk >> 16));
    }
    __syncthreads();
    unsigned s0 = nb_[ln] - b0, s1 = nb_[ln + 1] - b0;
    if (node < n) {
      float s = 0.f;
      for (unsigned j = s0; j < s1; ++j) {
        float ex = expf(aL[j * 8 + h]);
        aL[j * 8 + h] = ex;
        s += ex;
      }
      float inv = s > 0.f ? 1.f / s : 0.f;
      for (unsigned j = s0; j < s1; ++j) aL[j * 8 + h] *= inv;
    }
    __syncthreads();
    if (node < n) {
      float s = 0.f;
      for (unsigned j = s0; j < s1; ++j) {
        const float* a = &aL[j * 8];
        float w = B2[h];
#pragma unroll
        for (int kk = 0; kk < 8; ++kk) {
          float acc = B1[kk];
#pragma unroll
          for (int m = 0; m < 8; ++m) acc += a[m] * W1[kk * 8 + m];
          acc = acc > 0.f ? acc : 0.f;
          w += acc * W2[h * 8 + kk];
        }
        s += 1.f - w;
      }
      swD[(size_t)node * 8 + h] = s;
    }
    for (unsigned eL = t; eL < count; eL += 256) {
      const float* a = &aL[eL * 8];
      unsigned ee = eidD[b0 + eL];
      float4* op = (float4*)&attn[(size_t)ee * 8];
      op[0] = make_float4(a[0], a[1], a[2], a[3]);
      op[1] = make_float4(a[4], a[5], a[6], a[7]);
      unsigned q0 = (unsigned)f2bf(a[0]) | ((unsigned)f2bf(a[1]) << 16);
      unsigned q1 = (unsigned)f2bf(a[2]) | ((unsigned)f2bf(a[3]) << 16);
      unsigned q2 = (unsigned)f2bf(a[4]) | ((unsigned)f2bf(a[5]) << 16);
      unsigned q3 = (unsigned)f2bf(a[6]) | ((unsigned)f2bf(a[7]) << 16);
      *(uint4*)&apermB[(size_t)(b0 + eL) * 8] = make_uint4(q0, q1, q2, q3);
    }
  } else {
    unsigned sb = nb_[ln], se = nb_[ln + 1];
    if (node < n) {
      float s = 0.f;
      for (unsigned j = sb; j < se; ++j) s += expf(bf2f(apermB[(size_t)j * 8 + h]));
      float inv = s > 0.f ? 1.f / s : 0.f;
      for (unsigned j = sb; j < se; ++j) {
        size_t p = (size_t)j * 8 + h;
        apermB[p] = f2bf(expf(bf2f(apermB[p])) * inv);
      }
    }
    __syncthreads();
    if (node < n) {
      float s = 0.f;
      for (unsigned j = sb; j < se; ++j) {
        float a[8];
#pragma unroll
        for (int m = 0; m < 8; ++m) a[m] = bf2f(apermB[(size_t)j * 8 + m]);
        float w = B2[h];
#pragma unroll
        for (int kk = 0; kk < 8; ++kk) {
          float acc = B1[kk];
#pragma unroll
          for (int m = 0; m < 8; ++m) acc += a[m] * W1[kk * 8 + m];
          acc = acc > 0.f ? acc : 0.f;
          w += acc * W2[h * 8 + kk];
        }
        s += 1.f - w;
      }
      swD[(size_t)node * 8 + h] = s;
    }
    for (unsigned eL = t; eL < count; eL += 256) {
      unsigned j = b0 + eL;
      float a[8];
#pragma unroll
      for (int m = 0; m < 8; ++m) a[m] = bf2f(apermB[(size_t)j * 8 + m]);
      unsigned ee = eidD[j];
      float4* op = (float4*)&attn[(size_t)ee * 8];
      op[0] = make_float4(a[0], a[1], a[2], a[3]);
      op[1] = make_float4(a[4], a[5], a[6], a[7]);
    }
  }
}

// K5: sum_w = swD + src-half (gather attn row by orig eid + recompute MLP) -> t_relu.
__global__ __launch_bounds__(256) void k_sumw_tr(const unsigned* __restrict__ roffS,
                                                 const unsigned* __restrict__ eidS,
                                                 const float* __restrict__ swD,
                                                 const float* __restrict__ attn,
                                                 const float* __restrict__ aw1,
                                                 const float* __restrict__ ab1,
                                                 const float* __restrict__ aw2,
                                                 const float* __restrict__ ab2,
                                                 const float* __restrict__ tw1,
                                                 const float* __restrict__ tb1,
                                                 float* __restrict__ tr, int n) {
  __shared__ float sw[32][9];
  __shared__ float W1[64], W2[64], B1[8], B2[8];
  int t = threadIdx.x;
  if (t < 64) { W1[t] = aw1[t]; W2[t] = aw2[t]; }
  else if (t < 72) { B1[t - 64] = ab1[t - 64]; B2[t - 64] = ab2[t - 64]; }
  __syncthreads();
  int ln = t >> 3, h = t & 7;
  int node = blockIdx.x * 32 + ln;
  if (node < n) {
    float s = swD[(size_t)node * 8 + h];
    unsigned b = roffS[node], en = roffS[node + 1];
    for (unsigned j = b; j < en; ++j) {
      unsigned eid = eidS[j];
      float4 a0 = *(const float4*)&attn[(size_t)eid * 8];
      float4 a1 = *(const float4*)&attn[(size_t)eid * 8 + 4];
      float a[8] = {a0.x, a0.y, a0.z, a0.w, a1.x, a1.y, a1.z, a1.w};
      float w = B2[h];
#pragma unroll
      for (int kk = 0; kk < 8; ++kk) {
        float acc = B1[kk];
#pragma unroll
        for (int m = 0; m < 8; ++m) acc += a[m] * W1[kk * 8 + m];
        acc = acc > 0.f ? acc : 0.f;
        w += acc * W2[h * 8 + kk];
      }
      s += 1.f - w;
    }
    sw[ln][h] = s;
  }
  __syncthreads();
  if (node < n) {
    const float* wv = &tw1[h * 8];
    float acc = tb1[h];
#pragma unroll
    for (int kk = 0; kk < 8; ++kk) acc += sw[ln][kk] * wv[kk];
    tr[(size_t)node * 8 + h] = acc > 0.f ? acc : 0.f;
  }
}

// K-msg (fused e_emb + BN stats): wave handles 4 nodes; lane owns 2 bf16
// features; 4-edge unroll for memory-level parallelism.
__global__ __launch_bounds__(256) void k_msg(const int* __restrict__ srcD,
                                             const unsigned* __restrict__ roff,
                                             const ushort_t* __restrict__ apermB,
                                             const ushort_t* __restrict__ featbf,
                                             const float* __restrict__ tr,
                                             const float* __restrict__ tw2,
                                             const float* __restrict__ tb2,
                                             const float* __restrict__ gat_bias,
                                             float* __restrict__ hout,
                                             float* __restrict__ partial, int n) {
  __shared__ float bn1[4][128], bn2[4][128];
  int t = threadIdx.x;
  int w = t >> 6, lane = t & 63;
  int col = lane * 2;
  int hh = lane >> 3;
  float w2a[8], w2b[8];
#pragma unroll
  for (int j = 0; j < 8; ++j) { w2a[j] = tw2[col * 8 + j]; w2b[j] = tw2[(col + 1) * 8 + j]; }
  float biasA = tb2[col] + gat_bias[col];
  float biasB = tb2[col + 1] + gat_bias[col + 1];
  float s1a = 0.f, s1b = 0.f, s2a = 0.f, s2b = 0.f;
  int nodeBase = blockIdx.x * 16 + w * 4;
  for (int ni = 0; ni < 4; ++ni) {
    int node = nodeBase + ni;
    if (node >= n) break;
    unsigned b = roff[node], en = roff[node + 1];
    float x0 = 0.f, x1 = 0.f;
    unsigned j = b;
    for (; j + 4 <= en; j += 4) {
      int sa = srcD[j], sb = srcD[j + 1], sc2 = srcD[j + 2], sd = srcD[j + 3];
      float av0 = bf2f(apermB[(size_t)j * 8 + hh]);
      float av1 = bf2f(apermB[(size_t)(j + 1) * 8 + hh]);
      float av2 = bf2f(apermB[(size_t)(j + 2) * 8 + hh]);
      float av3 = bf2f(apermB[(size_t)(j + 3) * 8 + hh]);
      unsigned p0 = *(const unsigned*)&featbf[(size_t)sa * 128 + col];
      unsigned p1 = *(const unsigned*)&featbf[(size_t)sb * 128 + col];
      unsigned p2 = *(const unsigned*)&featbf[(size_t)sc2 * 128 + col];
      unsigned p3 = *(const unsigned*)&featbf[(size_t)sd * 128 + col];
      x0 += bf2f((ushort_t)(p0 & 0xFFFFu)) * av0 + bf2f((ushort_t)(p1 & 0xFFFFu)) * av1 +
            bf2f((ushort_t)(p2 & 0xFFFFu)) * av2 + bf2f((ushort_t)(p3 & 0xFFFFu)) * av3;
      x1 += bf2f((ushort_t)(p0 >> 16)) * av0 + bf2f((ushort_t)(p1 >> 16)) * av1 +
            bf2f((ushort_t)(p2 >> 16)) * av2 + bf2f((ushort_t)(p3 >> 16)) * av3;
    }
    for (; j < en; ++j) {
      int sa = srcD[j];
      float av0 = bf2f(apermB[(size_t)j * 8 + hh]);
      unsigned p0 = *(const unsigned*)&featbf[(size_t)sa * 128 + col];
      x0 += bf2f((ushort_t)(p0 & 0xFFFFu)) * av0;
      x1 += bf2f((ushort_t)(p0 >> 16)) * av0;
    }
    const float* trn = &tr[(size_t)node * 8];
    float emA = biasA, emB = biasB;
#pragma unroll
    for (int jj = 0; jj < 8; ++jj) {
      float tv = trn[jj];
      emA += tv * w2a[jj];
      emB += tv * w2b[jj];
    }
    float v0 = x0 + emA, v1 = x1 + emB;
    *(float2*)&hout[(size_t)node * 128 + col] = make_float2(v0, v1);
    s1a += v0; s1b += v1; s2a += v0 * v0; s2b += v1 * v1;
  }
  bn1[w][col] = s1a; bn1[w][col + 1] = s1b;
  bn2[w][col] = s2a; bn2[w][col + 1] = s2b;
  __syncthreads();
  int f = t & 127;
  float acc;
  if (t < 128) acc = bn1[0][f] + bn1[1][f] + bn1[2][f] + bn1[3][f];
  else         acc = bn2[0][f] + bn2[1][f] + bn2[2][f] + bn2[3][f];
  partial[(size_t)blockIdx.x * 256 + t] = acc;
}

// Reduce per-block BN partials.
__global__ __launch_bounds__(256) void k_red(const float* __restrict__ partial,
                                             float* __restrict__ bnacc, int rows) {
  int t = threadIdx.x;
  int r0 = blockIdx.x * 13, r1 = r0 + 13;
  if (r1 > rows) r1 = rows;
  if (r0 >= r1) return;
  float acc = 0.f;
  for (int r = r0; r < r1; ++r) acc += partial[(size_t)r * 256 + t];
  atomicAdd(&bnacc[t], acc);
}

__global__ void k_bnfin(const float* __restrict__ bnsum, const float* __restrict__ bnsq,
                        const float* __restrict__ gamma, float* __restrict__ mu,
                        float* __restrict__ scale, int n) {
  int i = threadIdx.x;
  if (i < 128) {
    float m = bnsum[i] / (float)n;
    float v = bnsq[i] / (float)n - m * m;
    mu[i] = m;
    scale[i] = rsqrtf(v + 1e-5f) * gamma[i];
  }
}

// K7: out = h_in + elu((x - mu)*scale + beta)
__global__ void k_final(const float* __restrict__ hin, float* __restrict__ hout,
                        const float* __restrict__ mu, const float* __restrict__ scale,
                        const float* __restrict__ beta, int total4) {
  int i = blockIdx.x * blockDim.x + threadIdx.x;
  if (i >= total4) return;
  int c = (i & 31) * 4;
  float4 x = ((const float4*)hout)[i];
  float4 m4 = *(const float4*)&mu[c];
  float4 s4 = *(const float4*)&scale[c];
  float4 b4 = *(const float4*)&beta[c];
  float4 hi = ((const float4*)hin)[i];
  float y0 = (x.x - m4.x) * s4.x + b4.x;
  float y1 = (x.y - m4.y) * s4.y + b4.y;
  float y2 = (x.z - m4.z) * s4.z + b4.z;
  float y3 = (x.w - m4.w) * s4.w + b4.w;
  y0 = y0 > 0.f ? y0 : expm1f(y0);
  y1 = y1 > 0.f ? y1 : expm1f(y1);
  y2 = y2 > 0.f ? y2 : expm1f(y2);
  y3 = y3 > 0.f ? y3 : expm1f(y3);
  float4 o = make_float4(hi.x + y0, hi.y + y1, hi.z + y2, hi.w + y3);
  ((float4*)hout)[i] = o;
}

extern "C" void kernel_launch(void* const* d_in, const int* in_sizes, int n_in,
                              void* d_out, int out_size, void* d_ws, size_t ws_size,
                              hipStream_t stream) {
  const float* h_in     = (const float*)d_in[0];
  const int*   esrc     = (const int*)d_in[1];
  const int*   edst     = (const int*)d_in[2];
  const float* fc_w     = (const float*)d_in[4];
  const float* attn_l   = (const float*)d_in[5];
  const float* attn_r   = (const float*)d_in[6];
  const float* gat_bias = (const float*)d_in[7];
  const float* aw1      = (const float*)d_in[8];
  const float* ab1      = (const float*)d_in[9];
  const float* aw2      = (const float*)d_in[10];
  const float* ab2      = (const float*)d_in[11];
  const float* tw1      = (const float*)d_in[12];
  const float* tb1      = (const float*)d_in[13];
  const float* tw2      = (const float*)d_in[14];
  const float* tb2      = (const float*)d_in[15];
  const float* gamma    = (const float*)d_in[16];
  const float* beta     = (const float*)d_in[17];

  const int n = in_sizes[0] / 128;  // 50000
  const int e = in_sizes[1];        // 600000
  const int nbkt = CDIV(n, 256);    // 196
  const int gridMsg = CDIV(n, 16);  // 3125

  float* ws = (float*)d_ws;
  size_t OFF_FEAT  = 0;                          // n*128 ushorts = n*64 floats
  size_t OFF_EL    = OFF_FEAT + (size_t)n * 64;
  size_t OFF_ER    = OFF_EL + (size_t)n * 8;
  size_t OFF_ROFD  = OFF_ER + (size_t)n * 8;
  size_t OFF_ROFS  = OFF_ROFD + (size_t)(n + 16);
  size_t OFF_EIDD  = OFF_ROFS + (size_t)(n + 16);
  size_t OFF_SRCD  = OFF_EIDD + (size_t)e;
  size_t OFF_EIDS  = OFF_SRCD + (size_t)e;
  size_t OFF_APERM = OFF_EIDS + (size_t)e;       // bf16: e*8 ushorts = e*4 floats
  size_t OFF_PART  = OFF_APERM + (size_t)e * 4;
  size_t OFF_META  = OFF_PART + (size_t)gridMsg * 256;
  size_t OFF_BN    = OFF_META + 1200;

  ushort_t* featbf = (ushort_t*)(ws + OFF_FEAT);
  float*    el     = ws + OFF_EL;
  float*    er     = ws + OFF_ER;
  unsigned* roffD  = (unsigned*)(ws + OFF_ROFD);
  unsigned* roffS  = (unsigned*)(ws + OFF_ROFS);
  unsigned* eidD   = (unsigned*)(ws + OFF_EIDD);
  int*      srcD   = (int*)(ws + OFF_SRCD);
  unsigned* eidS   = (unsigned*)(ws + OFF_EIDS);
  ushort_t* apermB = (ushort_t*)(ws + OFF_APERM);
  float*    partial= ws + OFF_PART;
  unsigned* meta   = (unsigned*)(ws + OFF_META);
  float*    bnsum  = ws + OFF_BN;
  float*    bnsq   = bnsum + 128;
  float*    mu     = bnsum + 256;
  float*    scale  = bnsum + 384;
  float*    tr     = el;  // alias: el dead after k_finB_dst
  float*    swD    = er;  // alias: er dead after k_finB_dst

  float* hout = (float*)d_out;
  float* attn = (float*)d_out + (size_t)n * 128;
  uint2*    recD = (uint2*)attn;                          // dead once k_attn writes attn
  unsigned* recS = (unsigned*)(attn + (size_t)e * 2);

  hipMemsetAsync(meta, 0, 400 * sizeof(unsigned), stream);   // histD+histS
  hipMemsetAsync(bnsum, 0, 256 * sizeof(float), stream);
  size_t head = (size_t)n * 128 + (size_t)e * 8;
  if ((size_t)out_size > head)
    hipMemsetAsync((float*)d_out + head, 0, ((size_t)out_size - head) * sizeof(float), stream);

  k_gemm<<<CDIV(n, 64), 256, 0, stream>>>(h_in, fc_w, attn_l, attn_r, featbf, el, er, n);

  // bucket sort (both graphs)
  k_hist<<<CDIV(e, 4096), 256, 0, stream>>>(esrc, edst, meta, meta + 200, nbkt, e);
  k_bktscan<<<1, 256, 0, stream>>>(meta, roffD, roffS, nbkt, n, e);
  k_scatterA<<<CDIV(e, 4096), 256, 0, stream>>>(esrc, edst, meta + 400, meta + 600,
                                                recD, recS, nbkt, e);
  k_finB_dst<<<nbkt, 256, 0, stream>>>(recD, meta + 800, el, er, roffD, apermB, srcD,
                                       eidD, n);
  k_finB_src<<<nbkt, 256, 0, stream>>>(recS, meta + 1000, roffS, eidS, n);

  // fused softmax + edge MLP + dst-sum_w + attn writeback
  k_attn<<<CDIV(n, 32), 256, 0, stream>>>(roffD, eidD, apermB, aw1, ab1, aw2, ab2,
                                          attn, swD, n);
  k_sumw_tr<<<CDIV(n, 32), 256, 0, stream>>>(roffS, eidS, swD, attn, aw1, ab1, aw2, ab2,
                                             tw1, tb1, tr, n);

  // message aggregation + e_emb + BN partials
  k_msg<<<gridMsg, 256, 0, stream>>>(srcD, roffD, apermB, featbf, tr, tw2, tb2, gat_bias,
                                     hout, partial, n);
  k_red<<<CDIV(gridMsg, 13), 256, 0, stream>>>(partial, bnsum, gridMsg);
  k_bnfin<<<1, 128, 0, stream>>>(bnsum, bnsq, gamma, mu, scale, n);
  k_final<<<CDIV(n * 32, 256), 256, 0, stream>>>(h_in, hout, mu, scale, beta, n * 32);
}